// Round 9
// baseline (280.911 us; speedup 1.0000x reference)
//
#include <hip/hip_runtime.h>

#define B_   16
#define C_   512
#define HW_  1024
#define G_   32
#define CPG  16
#define EPS  1e-5f
#define CHW  ((size_t)C_ * HW_)        // 524288 elements per batch (c,hw)
#define HW2  ((size_t)HW_ * HW_)       // 1048576 elements per batch (hw,hw)
#define SCALE 0.044194173824159216f    // 512^-0.5

typedef __attribute__((ext_vector_type(8))) short bf16x8;
typedef __attribute__((ext_vector_type(4))) float f32x4;

__device__ inline unsigned short f2bf(float f) {
    union { float f; unsigned u; } v; v.f = f;
    unsigned r = v.u + 0x7fffu + ((v.u >> 16) & 1u);   // RNE
    return (unsigned short)(r >> 16);
}

__device__ inline void gload_lds16(const void* g, void* lds) {
    __builtin_amdgcn_global_load_lds(
        (const __attribute__((address_space(1))) void*)g,
        (__attribute__((address_space(3))) void*)lds,
        16, 0, 0);
}

// ---------------- fp32 -> bf16 weight convert (all 4 weights, one launch) ----
__global__ __launch_bounds__(256) void f2bf4_kernel(
    const float* __restrict__ w0, const float* __restrict__ w1,
    const float* __restrict__ w2, const float* __restrict__ w3,
    unsigned short* __restrict__ o0, unsigned short* __restrict__ o1,
    unsigned short* __restrict__ o2, unsigned short* __restrict__ o3)
{
    int wsel = blockIdx.x >> 8;
    int blk  = blockIdx.x & 255;
    const float* in = (wsel == 0) ? w0 : (wsel == 1) ? w1 : (wsel == 2) ? w2 : w3;
    unsigned short* out = (wsel == 0) ? o0 : (wsel == 1) ? o1 : (wsel == 2) ? o2 : o3;
    int i = (blk * 256 + threadIdx.x) * 4;
    float4 f = *reinterpret_cast<const float4*>(in + i);
    ushort4 o;
    o.x = f2bf(f.x); o.y = f2bf(f.y); o.z = f2bf(f.z); o.w = f2bf(f.w);
    *reinterpret_cast<ushort4*>(out + i) = o;
}

// ---------------- concat bq||bk -> bqk[1024] ----------------
__global__ __launch_bounds__(256) void bias_concat(
    const float* __restrict__ bq, const float* __restrict__ bk,
    float* __restrict__ bqk)
{
    const float* src = blockIdx.x ? bk : bq;
    bqk[blockIdx.x * 512 + threadIdx.x]       = src[threadIdx.x];
    bqk[blockIdx.x * 512 + 256 + threadIdx.x] = src[256 + threadIdx.x];
}

// ---------------- GN pass 1: per-(b,g) mean / rsqrt(var) ----------------
__global__ __launch_bounds__(256) void gn_stats(const float* __restrict__ x,
                                                float2* __restrict__ stats)
{
    int bg = blockIdx.x;                                  // 0..511
    const float4* xp = reinterpret_cast<const float4*>(x + (size_t)bg * CPG * HW_);
    const int N = CPG * HW_;                              // 16384

    float s = 0.f, ss = 0.f;
#pragma unroll
    for (int k = 0; k < 16; ++k) {
        float4 v = xp[threadIdx.x + k * 256];
        s  += v.x + v.y + v.z + v.w;
        ss += v.x * v.x + v.y * v.y + v.z * v.z + v.w * v.w;
    }
    for (int off = 32; off; off >>= 1) {
        s  += __shfl_down(s,  off, 64);
        ss += __shfl_down(ss, off, 64);
    }
    __shared__ float red0[4], red1[4];
    int lane = threadIdx.x & 63, wid = threadIdx.x >> 6;
    if (lane == 0) { red0[wid] = s; red1[wid] = ss; }
    __syncthreads();
    if (threadIdx.x == 0) {
        float S  = red0[0] + red0[1] + red0[2] + red0[3];
        float SS = red1[0] + red1[1] + red1[2] + red1[3];
        float mu = S / (float)N;
        float var = SS / (float)N - mu * mu;
        stats[bg] = make_float2(mu, rsqrtf(var + EPS));
    }
}

// ---------------- GN pass 2: normalize + transpose -> bf16 hn_t[b][i][c] ----
__global__ __launch_bounds__(256) void gn_apply(
    const float* __restrict__ x, const float2* __restrict__ stats,
    const float* __restrict__ scale, const float* __restrict__ bias,
    unsigned short* __restrict__ hn_t)
{
    __shared__ unsigned short tile[64][72];

    const int b  = blockIdx.z;
    const int c0 = blockIdx.y * 64;
    const int i0 = blockIdx.x * 64;
    const int t  = threadIdx.x;

    const int r = t >> 2;
    const int q = t & 3;
    const int c = c0 + r;

    float2 st = stats[b * G_ + (c >> 4)];
    float scl = scale[c] * st.y;
    float bia = bias[c] - st.x * scl;

    const float* xp = x + ((size_t)b * C_ + c) * HW_ + i0 + q * 16;
#pragma unroll
    for (int u = 0; u < 4; ++u) {
        float4 v = *reinterpret_cast<const float4*>(xp + u * 4);
        int il = q * 16 + u * 4;
        tile[il + 0][r] = f2bf(v.x * scl + bia);
        tile[il + 1][r] = f2bf(v.y * scl + bia);
        tile[il + 2][r] = f2bf(v.z * scl + bia);
        tile[il + 3][r] = f2bf(v.w * scl + bia);
    }
    __syncthreads();

    const int il = t >> 2;
    unsigned short* dst = hn_t + ((size_t)b * HW_ + i0 + il) * C_ + c0;
    *reinterpret_cast<uint4*>(dst + q * 8)        = *reinterpret_cast<uint4*>(&tile[il][q * 8]);
    *reinterpret_cast<uint4*>(dst + (q + 4) * 8)  = *reinterpret_cast<uint4*>(&tile[il][(q + 4) * 8]);
}

// ================= 256x128 NT bf16 MFMA GEMM, 8-phase pipeline ==============
// (unchanged — used for QK-proj, V-proj, O-proj)
template<int OUTF32, int BIASMODE, int HASRES>
__global__ __launch_bounds__(512) void gemm_8p(
    const short* __restrict__ A, size_t sA, int ldA,
    const short* __restrict__ Bm, size_t sB, int ldB,
    void* __restrict__ Cm, size_t sC, int ldC,
    const float* __restrict__ bias,
    const float* __restrict__ res, size_t sR,
    int K, float alpha)
{
    __shared__ __align__(16) short lds[49152];    // 96 KB

    const int bz = blockIdx.z;
    const short* Ab = A  + (size_t)bz * sA;
    const short* Bb = Bm + (size_t)bz * sB;
    const int m0 = blockIdx.y * 256;
    const int n0 = blockIdx.x * 128;

    const int t = threadIdx.x;
    const int wv = t >> 6, lane = t & 63;
    const int wm = wv >> 1, wn = wv & 1;
    const int fr = lane & 15;
    const int cb = (lane >> 4) * 16;

    size_t srcA0, srcA1, srcB;
    {
        int p0 = t * 16;
        int a0 = p0 ^ (((p0 >> 7) & 3) << 4);
        srcA0 = (size_t)(m0 + (a0 >> 6)) * ldA + ((a0 & 63) >> 1);
        int p1 = 8192 + t * 16;
        int a1 = p1 ^ (((p1 >> 7) & 3) << 4);
        srcA1 = (size_t)(m0 + (a1 >> 6)) * ldA + ((a1 & 63) >> 1);
        srcB  = (size_t)(n0 + (a0 >> 6)) * ldB + ((a0 & 63) >> 1);
    }
    auto stageA = [&](int par, int kh, int kt_src) {
        const short* s = Ab + kt_src * 64 + kh * 32;
        short* d = &lds[(par * 2 + kh) * 8192 + wv * 512];
        gload_lds16(s + srcA0, d);
        gload_lds16(s + srcA1, d + 4096);
    };
    auto stageB = [&](int par, int kh, int kt_src) {
        const short* s = Bb + kt_src * 64 + kh * 32;
        gload_lds16(s + srcB, &lds[32768 + (par * 2 + kh) * 4096 + wv * 512]);
    };

    int aoffs[4], boffs[4];
#pragma unroll
    for (int fi = 0; fi < 4; ++fi) {
        int row = wm * 64 + fi * 16 + fr;
        int off = row * 64 + cb;
        aoffs[fi] = off ^ (((off >> 7) & 3) << 4);
    }
#pragma unroll
    for (int fj = 0; fj < 4; ++fj) {
        int row = wn * 64 + fj * 16 + fr;
        int off = row * 64 + cb;
        boffs[fj] = off ^ (((off >> 7) & 3) << 4);
    }

    f32x4 acc[4][4];
#pragma unroll
    for (int i = 0; i < 4; ++i)
#pragma unroll
        for (int j = 0; j < 4; ++j) acc[i][j] = (f32x4){0.f, 0.f, 0.f, 0.f};

    const int NT = K >> 6;
    const char* L = (const char*)lds;

    stageA(0, 0, 0); stageB(0, 0, 0);
    stageA(0, 1, 0); stageB(0, 1, 0);
    stageA(1, 0, 1); stageB(1, 0, 1);

    for (int kt = 0; kt < NT; ++kt) {
        const int par = kt & 1;
        const int AB0 = (par * 2) * 16384;
        const int AB1 = AB0 + 16384;
        const int BB0 = 65536 + (par * 2) * 8192;
        const int BB1 = BB0 + 8192;

        bf16x8 af0, af1, af2, af3, bf0, bf1;

        if (kt == NT - 1) asm volatile("s_waitcnt vmcnt(3)\n\ts_barrier" ::: "memory");
        else              asm volatile("s_waitcnt vmcnt(6)\n\ts_barrier" ::: "memory");
        af0 = *(const bf16x8*)(L + AB0 + aoffs[0]);
        af1 = *(const bf16x8*)(L + AB0 + aoffs[1]);
        af2 = *(const bf16x8*)(L + AB0 + aoffs[2]);
        af3 = *(const bf16x8*)(L + AB0 + aoffs[3]);
        bf0 = *(const bf16x8*)(L + BB0 + boffs[0]);
        bf1 = *(const bf16x8*)(L + BB0 + boffs[1]);
        if (kt + 1 < NT) stageA(par ^ 1, 1, kt + 1);
        __builtin_amdgcn_s_setprio(1);
        acc[0][0] = __builtin_amdgcn_mfma_f32_16x16x32_bf16(af0, bf0, acc[0][0], 0, 0, 0);
        acc[1][0] = __builtin_amdgcn_mfma_f32_16x16x32_bf16(af1, bf0, acc[1][0], 0, 0, 0);
        acc[2][0] = __builtin_amdgcn_mfma_f32_16x16x32_bf16(af2, bf0, acc[2][0], 0, 0, 0);
        acc[3][0] = __builtin_amdgcn_mfma_f32_16x16x32_bf16(af3, bf0, acc[3][0], 0, 0, 0);
        acc[0][1] = __builtin_amdgcn_mfma_f32_16x16x32_bf16(af0, bf1, acc[0][1], 0, 0, 0);
        acc[1][1] = __builtin_amdgcn_mfma_f32_16x16x32_bf16(af1, bf1, acc[1][1], 0, 0, 0);
        acc[2][1] = __builtin_amdgcn_mfma_f32_16x16x32_bf16(af2, bf1, acc[2][1], 0, 0, 0);
        acc[3][1] = __builtin_amdgcn_mfma_f32_16x16x32_bf16(af3, bf1, acc[3][1], 0, 0, 0);
        __builtin_amdgcn_s_setprio(0);
        asm volatile("s_waitcnt lgkmcnt(0)\n\ts_barrier" ::: "memory");

        bf0 = *(const bf16x8*)(L + BB0 + boffs[2]);
        bf1 = *(const bf16x8*)(L + BB0 + boffs[3]);
        if (kt + 1 < NT) stageB(par ^ 1, 1, kt + 1);
        __builtin_amdgcn_s_setprio(1);
        acc[0][2] = __builtin_amdgcn_mfma_f32_16x16x32_bf16(af0, bf0, acc[0][2], 0, 0, 0);
        acc[1][2] = __builtin_amdgcn_mfma_f32_16x16x32_bf16(af1, bf0, acc[1][2], 0, 0, 0);
        acc[2][2] = __builtin_amdgcn_mfma_f32_16x16x32_bf16(af2, bf0, acc[2][2], 0, 0, 0);
        acc[3][2] = __builtin_amdgcn_mfma_f32_16x16x32_bf16(af3, bf0, acc[3][2], 0, 0, 0);
        acc[0][3] = __builtin_amdgcn_mfma_f32_16x16x32_bf16(af0, bf1, acc[0][3], 0, 0, 0);
        acc[1][3] = __builtin_amdgcn_mfma_f32_16x16x32_bf16(af1, bf1, acc[1][3], 0, 0, 0);
        acc[2][3] = __builtin_amdgcn_mfma_f32_16x16x32_bf16(af2, bf1, acc[2][3], 0, 0, 0);
        acc[3][3] = __builtin_amdgcn_mfma_f32_16x16x32_bf16(af3, bf1, acc[3][3], 0, 0, 0);
        __builtin_amdgcn_s_setprio(0);
        asm volatile("s_waitcnt lgkmcnt(0)\n\ts_barrier" ::: "memory");

        if (kt == NT - 1) asm volatile("s_waitcnt vmcnt(0)\n\ts_barrier" ::: "memory");
        else              asm volatile("s_waitcnt vmcnt(6)\n\ts_barrier" ::: "memory");
        af0 = *(const bf16x8*)(L + AB1 + aoffs[0]);
        af1 = *(const bf16x8*)(L + AB1 + aoffs[1]);
        af2 = *(const bf16x8*)(L + AB1 + aoffs[2]);
        af3 = *(const bf16x8*)(L + AB1 + aoffs[3]);
        bf0 = *(const bf16x8*)(L + BB1 + boffs[0]);
        bf1 = *(const bf16x8*)(L + BB1 + boffs[1]);
        if (kt + 2 < NT) stageA(par, 0, kt + 2);
        __builtin_amdgcn_s_setprio(1);
        acc[0][0] = __builtin_amdgcn_mfma_f32_16x16x32_bf16(af0, bf0, acc[0][0], 0, 0, 0);
        acc[1][0] = __builtin_amdgcn_mfma_f32_16x16x32_bf16(af1, bf0, acc[1][0], 0, 0, 0);
        acc[2][0] = __builtin_amdgcn_mfma_f32_16x16x32_bf16(af2, bf0, acc[2][0], 0, 0, 0);
        acc[3][0] = __builtin_amdgcn_mfma_f32_16x16x32_bf16(af3, bf0, acc[3][0], 0, 0, 0);
        acc[0][1] = __builtin_amdgcn_mfma_f32_16x16x32_bf16(af0, bf1, acc[0][1], 0, 0, 0);
        acc[1][1] = __builtin_amdgcn_mfma_f32_16x16x32_bf16(af1, bf1, acc[1][1], 0, 0, 0);
        acc[2][1] = __builtin_amdgcn_mfma_f32_16x16x32_bf16(af2, bf1, acc[2][1], 0, 0, 0);
        acc[3][1] = __builtin_amdgcn_mfma_f32_16x16x32_bf16(af3, bf1, acc[3][1], 0, 0, 0);
        __builtin_amdgcn_s_setprio(0);
        asm volatile("s_waitcnt lgkmcnt(0)\n\ts_barrier" ::: "memory");

        bf0 = *(const bf16x8*)(L + BB1 + boffs[2]);
        bf1 = *(const bf16x8*)(L + BB1 + boffs[3]);
        if (kt + 2 < NT) stageB(par, 0, kt + 2);
        __builtin_amdgcn_s_setprio(1);
        acc[0][2] = __builtin_amdgcn_mfma_f32_16x16x32_bf16(af0, bf0, acc[0][2], 0, 0, 0);
        acc[1][2] = __builtin_amdgcn_mfma_f32_16x16x32_bf16(af1, bf0, acc[1][2], 0, 0, 0);
        acc[2][2] = __builtin_amdgcn_mfma_f32_16x16x32_bf16(af2, bf0, acc[2][2], 0, 0, 0);
        acc[3][2] = __builtin_amdgcn_mfma_f32_16x16x32_bf16(af3, bf0, acc[3][2], 0, 0, 0);
        acc[0][3] = __builtin_amdgcn_mfma_f32_16x16x32_bf16(af0, bf1, acc[0][3], 0, 0, 0);
        acc[1][3] = __builtin_amdgcn_mfma_f32_16x16x32_bf16(af1, bf1, acc[1][3], 0, 0, 0);
        acc[2][3] = __builtin_amdgcn_mfma_f32_16x16x32_bf16(af2, bf1, acc[2][3], 0, 0, 0);
        acc[3][3] = __builtin_amdgcn_mfma_f32_16x16x32_bf16(af3, bf1, acc[3][3], 0, 0, 0);
        __builtin_amdgcn_s_setprio(0);
        asm volatile("s_waitcnt lgkmcnt(0)\n\ts_barrier" ::: "memory");
    }

    const int rq = (lane >> 4) * 4;
#pragma unroll
    for (int fi = 0; fi < 4; ++fi) {
#pragma unroll
        for (int rg = 0; rg < 4; ++rg) {
            int row = m0 + wm * 64 + fi * 16 + rq + rg;
            float bm = (BIASMODE == 1) ? bias[row] : 0.f;
#pragma unroll
            for (int fj = 0; fj < 4; ++fj) {
                int col = n0 + wn * 64 + fj * 16 + fr;
                float vv = acc[fi][fj][rg] * alpha + bm;
                if (BIASMODE == 2) vv += bias[col];
                size_t off = (size_t)row * ldC + col;
                if (HASRES) vv += res[(size_t)bz * sR + off];
                if (OUTF32) ((float*)Cm)[(size_t)bz * sC + off] = vv;
                else ((unsigned short*)Cm)[(size_t)bz * sC + off] = f2bf(vv);
            }
        }
    }
}

// ================= fused flash attention v2 ==================================
// grid 512: b = wg&15 (all 32 q-blocks of a batch land on XCD b%8), qb = wg>>4.
// QB=32, KVBLK=128, 8 tiles. 8 waves = 8 j-slices of 16.
// Q resident in VGPRs (2 halves x 16 ks). K and V fragments read DIRECTLY from
// global (L2-resident; no LDS staging, no vmcnt asm — compiler pipelines).
// Only P (subtiled+swizzled, 8KB) and the softmax partial exchange use LDS.
// Lane-local online softmax: each lane's PV acc rows == its softmax rows, so
// m/l/alpha never cross lanes; only per-j-slice partial max/sum cross waves.
// 2 barriers per tile (lgkmcnt only, loads stay in flight).
__global__ __launch_bounds__(512) void flash_attn(
    const short* __restrict__ qk_t,       // [b*1024][q(512)||k(512)]
    const short* __restrict__ vsrc,       // [b][512 c][1024 j]
    unsigned short* __restrict__ ao_t)    // [b*1024][512]
{
    __shared__ __align__(16) unsigned short Plds[4096];   // [4 ks2][32 q][32 j] swz, 8KB
    __shared__ float sM[32][12];          // partial max  [q][wave] (12: bank-spread)
    __shared__ float sS[32][12];          // partial sum

    const int wg = blockIdx.x;
    const int b  = wg & 15;
    const int qb = wg >> 4;               // 0..31
    const int t  = threadIdx.x;
    const int wv = t >> 6, lane = t & 63;
    const int l15 = lane & 15, l4 = lane >> 4;

    const short* Qg = qk_t + ((size_t)(b * 1024 + qb * 32)) * 1024;
    const short* Kg = qk_t + (size_t)(b * 1024) * 1024 + 512;
    const short* Vg = vsrc + (size_t)b * CHW;

    // Q resident: rows h*16+l15, k chunks l4*8 + ks*32
    bf16x8 qf[2][16];
#pragma unroll
    for (int h = 0; h < 2; ++h) {
        const short* qrow = Qg + (size_t)(h * 16 + l15) * 1024 + l4 * 8;
#pragma unroll
        for (int ks = 0; ks < 16; ++ks)
            qf[h][ks] = *(const bf16x8*)(qrow + ks * 32);
    }

    f32x4 acc[2][4];
#pragma unroll
    for (int h = 0; h < 2; ++h)
#pragma unroll
        for (int fj = 0; fj < 4; ++fj) acc[h][fj] = (f32x4){0.f, 0.f, 0.f, 0.f};
    float m_r[2][4], l_r[2][4];
#pragma unroll
    for (int h = 0; h < 2; ++h)
#pragma unroll
        for (int rg = 0; rg < 4; ++rg) { m_r[h][rg] = -1e30f; l_r[h][rg] = 0.f; }

    // per-lane fixed sub-addresses
    const short* Kl = Kg + (size_t)(wv * 16 + l15) * 1024 + l4 * 8;   // K frag row
    const short* Vl = Vg + (size_t)(wv * 64 + l15) * 1024 + l4 * 8;   // V frag row (fj adds 16 rows)

    // P write byte offsets (q-local ql, j-local jj), involution swz on chunk
    int pwb[2][4];
#pragma unroll
    for (int h = 0; h < 2; ++h)
#pragma unroll
        for (int rg = 0; rg < 4; ++rg) {
            int ql = h * 16 + l4 * 4 + rg;
            int jj = (wv & 1) * 16 + l15;
            pwb[h][rg] = (wv >> 1) * 2048 + ql * 64 + ((jj * 2) ^ (((ql >> 1) & 3) << 4));
        }
    // P read byte offsets per fi (ks2 adds 2048 each)
    int prb[2];
#pragma unroll
    for (int fi = 0; fi < 2; ++fi) {
        int row = fi * 16 + l15;
        prb[fi] = row * 64 + ((l4 * 16) ^ (((row >> 1) & 3) << 4));
    }

    for (int tkv = 0; tkv < 8; ++tkv) {
        // ---- QK^T: S[32 q][16 j-slice], K frags straight from L2
        const short* Kt = Kl + (size_t)tkv * 128 * 1024;
        f32x4 s0 = (f32x4){0.f,0.f,0.f,0.f}, s1 = (f32x4){0.f,0.f,0.f,0.f};
#pragma unroll
        for (int ks = 0; ks < 16; ++ks) {
            bf16x8 kf = *(const bf16x8*)(Kt + ks * 32);
            s0 = __builtin_amdgcn_mfma_f32_16x16x32_bf16(qf[0][ks], kf, s0, 0, 0, 0);
            s1 = __builtin_amdgcn_mfma_f32_16x16x32_bf16(qf[1][ks], kf, s1, 0, 0, 0);
        }

        // ---- partial row-max over this wave's 16 j
        float u[2][4];
#pragma unroll
        for (int rg = 0; rg < 4; ++rg) { u[0][rg] = s0[rg] * SCALE; u[1][rg] = s1[rg] * SCALE; }
#pragma unroll
        for (int h = 0; h < 2; ++h)
#pragma unroll
            for (int rg = 0; rg < 4; ++rg) {
                float mx = u[h][rg];
                mx = fmaxf(mx, __shfl_xor(mx, 1));
                mx = fmaxf(mx, __shfl_xor(mx, 2));
                mx = fmaxf(mx, __shfl_xor(mx, 4));
                mx = fmaxf(mx, __shfl_xor(mx, 8));
                if (l15 == 0) sM[h * 16 + l4 * 4 + rg][wv] = mx;
            }
        asm volatile("s_waitcnt lgkmcnt(0)\n\ts_barrier" ::: "memory");   // bar1

        // ---- global max, alpha, P, partial sums
        float al[2][4];
#pragma unroll
        for (int h = 0; h < 2; ++h)
#pragma unroll
            for (int rg = 0; rg < 4; ++rg) {
                int ql = h * 16 + l4 * 4 + rg;
                float4 x0 = *reinterpret_cast<const float4*>(&sM[ql][0]);
                float4 x1 = *reinterpret_cast<const float4*>(&sM[ql][4]);
                float tmax = fmaxf(fmaxf(fmaxf(x0.x, x0.y), fmaxf(x0.z, x0.w)),
                                   fmaxf(fmaxf(x1.x, x1.y), fmaxf(x1.z, x1.w)));
                float mn = fmaxf(m_r[h][rg], tmax);
                al[h][rg] = __expf(m_r[h][rg] - mn);
                m_r[h][rg] = mn;
                float p = __expf(u[h][rg] - mn);
                float ps = p;
                ps += __shfl_xor(ps, 1); ps += __shfl_xor(ps, 2);
                ps += __shfl_xor(ps, 4); ps += __shfl_xor(ps, 8);
                if (l15 == 0) sS[ql][wv] = ps;
                *(unsigned short*)((char*)Plds + pwb[h][rg]) = f2bf(p);
            }
        asm volatile("s_waitcnt lgkmcnt(0)\n\ts_barrier" ::: "memory");   // bar2

        // ---- l update + O rescale (all lane-local)
#pragma unroll
        for (int h = 0; h < 2; ++h)
#pragma unroll
            for (int rg = 0; rg < 4; ++rg) {
                int ql = h * 16 + l4 * 4 + rg;
                float4 y0 = *reinterpret_cast<const float4*>(&sS[ql][0]);
                float4 y1 = *reinterpret_cast<const float4*>(&sS[ql][4]);
                float ts = (y0.x + y0.y) + (y0.z + y0.w) + (y1.x + y1.y) + (y1.z + y1.w);
                l_r[h][rg] = l_r[h][rg] * al[h][rg] + ts;
#pragma unroll
                for (int fj = 0; fj < 4; ++fj) acc[h][fj][rg] *= al[h][rg];
            }

        // ---- PV: O[32 q][64 d-slice] += P x V, V frags straight from L2
        const short* Vt = Vl + tkv * 128;
#pragma unroll
        for (int ks2 = 0; ks2 < 4; ++ks2) {
            bf16x8 pf0 = *(const bf16x8*)((const char*)Plds + ks2 * 2048 + prb[0]);
            bf16x8 pf1 = *(const bf16x8*)((const char*)Plds + ks2 * 2048 + prb[1]);
            bf16x8 vf[4];
#pragma unroll
            for (int fj = 0; fj < 4; ++fj)
                vf[fj] = *(const bf16x8*)(Vt + (size_t)(fj * 16) * 1024 + ks2 * 32);
#pragma unroll
            for (int fj = 0; fj < 4; ++fj) {
                acc[0][fj] = __builtin_amdgcn_mfma_f32_16x16x32_bf16(pf0, vf[fj], acc[0][fj], 0, 0, 0);
                acc[1][fj] = __builtin_amdgcn_mfma_f32_16x16x32_bf16(pf1, vf[fj], acc[1][fj], 0, 0, 0);
            }
        }
        // next tile's bar1 protects P and sM/sS overwrite
    }

    // ---- epilogue: divide by l, write ao_t rows q0.., cols d = wv*64..
    unsigned short* aob = ao_t + ((size_t)(b * 1024 + qb * 32)) * 512 + wv * 64;
#pragma unroll
    for (int fi = 0; fi < 2; ++fi)
#pragma unroll
        for (int rg = 0; rg < 4; ++rg) {
            int row = fi * 16 + l4 * 4 + rg;
            float inv = 1.0f / l_r[fi][rg];
#pragma unroll
            for (int fj = 0; fj < 4; ++fj)
                aob[(size_t)row * 512 + fj * 16 + l15] = f2bf(acc[fi][fj][rg] * inv);
        }
}

extern "C" void kernel_launch(void* const* d_in, const int* in_sizes, int n_in,
                              void* d_out, int out_size, void* d_ws, size_t ws_size,
                              hipStream_t stream)
{
    const float* x        = (const float*)d_in[0];
    // d_in[1] = temb : unused by the reference
    const float* gn_scale = (const float*)d_in[2];
    const float* gn_bias  = (const float*)d_in[3];
    const float* wq = (const float*)d_in[4];
    const float* bq = (const float*)d_in[5];
    const float* wk = (const float*)d_in[6];
    const float* bk = (const float*)d_in[7];
    const float* wv = (const float*)d_in[8];
    const float* bv = (const float*)d_in[9];
    const float* wo = (const float*)d_in[10];
    const float* bo = (const float*)d_in[11];
    float* out = (float*)d_out;

    // workspace layout (bf16 elements)
    short* ws = (short*)d_ws;
    const size_t E = (size_t)B_ * C_ * HW_;        // 8388608
    short* hn_t = ws;                              // [b][i][c]          E
    short* qk_t = hn_t + E;                        // [b*i][q||k]        2E
    short* v    = qk_t + 2 * E;                    // [b][c][j]          E
    short* ao_t = v + E;                           // [b][i][c]          E
    short* attn = ao_t + E;                        // (unused)           2E
    short* wsq  = attn + 2 * E;                    // wq||wk||wv||wo bf16
    short* wsk  = wsq + (size_t)C_ * C_;
    short* wsv  = wsk + (size_t)C_ * C_;
    short* wso  = wsv + (size_t)C_ * C_;
    float* bqk  = (float*)(wso + (size_t)C_ * C_); // 1024 f32
    float2* stats = (float2*)(bqk + 1024);         // 512 float2

    f2bf4_kernel<<<dim3(1024), 256, 0, stream>>>(
        wq, wk, wv, wo,
        (unsigned short*)wsq, (unsigned short*)wsk,
        (unsigned short*)wsv, (unsigned short*)wso);
    bias_concat<<<dim3(2), 256, 0, stream>>>(bq, bk, bqk);

    gn_stats<<<dim3(B_ * G_), 256, 0, stream>>>(x, stats);
    gn_apply<<<dim3(HW_ / 64, C_ / 64, B_), 256, 0, stream>>>(
        x, stats, gn_scale, gn_bias, (unsigned short*)hn_t);

    // fused QK projection: qk_t[m][n] = sum_c hn_t[m][c] * (wq||wk)[n][c] + bqk[n]
    dim3 gqk(HW_ / 128, (B_ * HW_) / 256, 1);      // (8, 64, 1)
    gemm_8p<0, 2, 0><<<gqk, 512, 0, stream>>>(
        hn_t, 0, C_, wsq, 0, C_, qk_t, 0, HW_, bqk, nullptr, 0, C_, 1.0f);

    // v[c][j] = sum_k wv[c][k] * hn_t[j][k] + bv[c]
    dim3 gv(HW_ / 128, C_ / 256, B_);              // (8, 2, 16)
    gemm_8p<0, 1, 0><<<gv, 512, 0, stream>>>(
        wsv, 0, C_, hn_t, CHW, C_, v, CHW, HW_, bv, nullptr, 0, C_, 1.0f);

    // fused attention: scores + softmax + PV  ->  ao_t[i][c]
    flash_attn<<<dim3(512), 512, 0, stream>>>(qk_t, v, (unsigned short*)ao_t);

    // out[c][i] = x + sum_k wo[c][k] * ao_t[i][k] + bo[c]
    dim3 go(HW_ / 128, C_ / 256, B_);              // (8, 2, 16)
    gemm_8p<1, 1, 1><<<go, 512, 0, stream>>>(
        wso, 0, C_, ao_t, CHW, C_, out, CHW, HW_, bo, x, CHW, C_, 1.0f);
}

// Round 10
// 164.570 us; speedup vs baseline: 1.7069x; 1.7069x over previous
//
#include <hip/hip_runtime.h>

#define B_   16
#define C_   512
#define HW_  1024
#define G_   32
#define CPG  16
#define EPS  1e-5f
#define CHW  ((size_t)C_ * HW_)        // 524288 elements per batch (c,hw)
#define HW2  ((size_t)HW_ * HW_)       // 1048576 elements per batch (hw,hw)

typedef __attribute__((ext_vector_type(8))) short bf16x8;
typedef __attribute__((ext_vector_type(4))) float f32x4;

__device__ inline unsigned short f2bf(float f) {
    union { float f; unsigned u; } v; v.f = f;
    unsigned r = v.u + 0x7fffu + ((v.u >> 16) & 1u);   // RNE
    return (unsigned short)(r >> 16);
}
__device__ inline float bf2f(unsigned short h) {
    union { unsigned u; float f; } v; v.u = (unsigned)h << 16;
    return v.f;
}

__device__ inline void gload_lds16(const void* g, void* lds) {
    __builtin_amdgcn_global_load_lds(
        (const __attribute__((address_space(1))) void*)g,
        (__attribute__((address_space(3))) void*)lds,
        16, 0, 0);
}

// ---------------- fp32 -> bf16 weight convert (all 4 weights, one launch) ----
__global__ __launch_bounds__(256) void f2bf4_kernel(
    const float* __restrict__ w0, const float* __restrict__ w1,
    const float* __restrict__ w2, const float* __restrict__ w3,
    unsigned short* __restrict__ o0, unsigned short* __restrict__ o1,
    unsigned short* __restrict__ o2, unsigned short* __restrict__ o3)
{
    int wsel = blockIdx.x >> 8;
    int blk  = blockIdx.x & 255;
    const float* in = (wsel == 0) ? w0 : (wsel == 1) ? w1 : (wsel == 2) ? w2 : w3;
    unsigned short* out = (wsel == 0) ? o0 : (wsel == 1) ? o1 : (wsel == 2) ? o2 : o3;
    int i = (blk * 256 + threadIdx.x) * 4;
    float4 f = *reinterpret_cast<const float4*>(in + i);
    ushort4 o;
    o.x = f2bf(f.x); o.y = f2bf(f.y); o.z = f2bf(f.z); o.w = f2bf(f.w);
    *reinterpret_cast<ushort4*>(out + i) = o;
}

// ---------------- concat bq||bk -> bqk[1024] ----------------
__global__ __launch_bounds__(256) void bias_concat(
    const float* __restrict__ bq, const float* __restrict__ bk,
    float* __restrict__ bqk)
{
    const float* src = blockIdx.x ? bk : bq;
    bqk[blockIdx.x * 512 + threadIdx.x]       = src[threadIdx.x];
    bqk[blockIdx.x * 512 + 256 + threadIdx.x] = src[256 + threadIdx.x];
}

// ---------------- GN pass 1: per-(b,g) mean / rsqrt(var) ----------------
__global__ __launch_bounds__(256) void gn_stats(const float* __restrict__ x,
                                                float2* __restrict__ stats)
{
    int bg = blockIdx.x;                                  // 0..511
    const float4* xp = reinterpret_cast<const float4*>(x + (size_t)bg * CPG * HW_);
    const int N = CPG * HW_;                              // 16384

    float s = 0.f, ss = 0.f;
#pragma unroll
    for (int k = 0; k < 16; ++k) {
        float4 v = xp[threadIdx.x + k * 256];
        s  += v.x + v.y + v.z + v.w;
        ss += v.x * v.x + v.y * v.y + v.z * v.z + v.w * v.w;
    }
    for (int off = 32; off; off >>= 1) {
        s  += __shfl_down(s,  off, 64);
        ss += __shfl_down(ss, off, 64);
    }
    __shared__ float red0[4], red1[4];
    int lane = threadIdx.x & 63, wid = threadIdx.x >> 6;
    if (lane == 0) { red0[wid] = s; red1[wid] = ss; }
    __syncthreads();
    if (threadIdx.x == 0) {
        float S  = red0[0] + red0[1] + red0[2] + red0[3];
        float SS = red1[0] + red1[1] + red1[2] + red1[3];
        float mu = S / (float)N;
        float var = SS / (float)N - mu * mu;
        stats[bg] = make_float2(mu, rsqrtf(var + EPS));
    }
}

// ---------------- GN pass 2: normalize + transpose -> bf16 hn_t[b][i][c] ----
__global__ __launch_bounds__(256) void gn_apply(
    const float* __restrict__ x, const float2* __restrict__ stats,
    const float* __restrict__ scale, const float* __restrict__ bias,
    unsigned short* __restrict__ hn_t)
{
    __shared__ unsigned short tile[64][72];

    const int b  = blockIdx.z;
    const int c0 = blockIdx.y * 64;
    const int i0 = blockIdx.x * 64;
    const int t  = threadIdx.x;

    const int r = t >> 2;
    const int q = t & 3;
    const int c = c0 + r;

    float2 st = stats[b * G_ + (c >> 4)];
    float scl = scale[c] * st.y;
    float bia = bias[c] - st.x * scl;

    const float* xp = x + ((size_t)b * C_ + c) * HW_ + i0 + q * 16;
#pragma unroll
    for (int u = 0; u < 4; ++u) {
        float4 v = *reinterpret_cast<const float4*>(xp + u * 4);
        int il = q * 16 + u * 4;
        tile[il + 0][r] = f2bf(v.x * scl + bia);
        tile[il + 1][r] = f2bf(v.y * scl + bia);
        tile[il + 2][r] = f2bf(v.z * scl + bia);
        tile[il + 3][r] = f2bf(v.w * scl + bia);
    }
    __syncthreads();

    const int il = t >> 2;
    unsigned short* dst = hn_t + ((size_t)b * HW_ + i0 + il) * C_ + c0;
    *reinterpret_cast<uint4*>(dst + q * 8)        = *reinterpret_cast<uint4*>(&tile[il][q * 8]);
    *reinterpret_cast<uint4*>(dst + (q + 4) * 8)  = *reinterpret_cast<uint4*>(&tile[il][(q + 4) * 8]);
}

// ====== 128x128 NT bf16 MFMA GEMM, 4-phase counted-vmcnt, 2 blocks/CU =======
// C[m][n] = alpha * sum_k A[m*ldA+k] * B[n*ldB+k]  (+bias) (+res)
// BM=BN=128, BK=64. 256 thr = 4 waves (2M x 2N), wave tile 64x64
// (acc 4x4 frags of 16x16x32). LDS = 64 KB -> 2 blocks/CU: fine phases AND
// cross-block overlap (r7 had fine phases at 1 blk/CU; r6 had 3 blk/CU with
// coarse phases; this combines them).
// Slots (8 KB = [128 rows][32 shorts] each): A[par][kh] bytes (par*2+kh)*8192,
// B[par][kh] at +32768. Per kt, 4 phases (ks, jh):
//   ph0: [wait vmcnt + bar] read af0-3(ks0)+bf01, stage A(kt+1)k1, 8 MFMA
//   ph1: read bf23, stage B(kt+1)k1, 8 MFMA, [lgkm0+bar]
//   ph2: [wait vmcnt + bar] read af(ks1)+bf01, stage A(kt+2)k0, 8 MFMA
//   ph3: read bf23, stage B(kt+2)k0, 8 MFMA, [lgkm0+bar]
// Each stage = 2 per-thread 16B loads. Steady-state queue = 12 loads; waits
// are vmcnt(8) at ph0/ph2 (oldest slot pair landed); last kt: 4 then 0.
// Swizzle (involution, proven r5-r7): off ^= ((off>>7)&3)<<4 within slot;
// linear gload dest, pre-swizzled global source, swizzled ds_read offsets.
// BIASMODE: 0 none, 1 per-row bias[m], 2 per-col bias[n].
template<int OUTF32, int BIASMODE, int HASRES>
__global__ __launch_bounds__(256) void gemm_4w(
    const short* __restrict__ A, size_t sA, int ldA,
    const short* __restrict__ Bm, size_t sB, int ldB,
    void* __restrict__ Cm, size_t sC, int ldC,
    const float* __restrict__ bias,
    const float* __restrict__ res, size_t sR,
    int K, float alpha)
{
    __shared__ __align__(16) short lds[32768];    // 64 KB

    const int bz = blockIdx.z;
    const short* Ab = A  + (size_t)bz * sA;
    const short* Bb = Bm + (size_t)bz * sB;
    const int m0 = blockIdx.y * 128;
    const int n0 = blockIdx.x * 128;

    const int t = threadIdx.x;
    const int wv = t >> 6, lane = t & 63;
    const int wm = wv >> 1, wn = wv & 1;
    const int fr = lane & 15;
    const int cb = (lane >> 4) * 16;

    // staging source offsets (pre-swizzled) for the two 4KB halves of a slot
    size_t srcA0, srcA1, srcB0, srcB1;
    {
        int p0 = t * 16;
        int a0 = p0 ^ (((p0 >> 7) & 3) << 4);
        int p1 = 4096 + t * 16;
        int a1 = p1 ^ (((p1 >> 7) & 3) << 4);
        srcA0 = (size_t)(m0 + (a0 >> 6)) * ldA + ((a0 & 63) >> 1);
        srcA1 = (size_t)(m0 + (a1 >> 6)) * ldA + ((a1 & 63) >> 1);
        srcB0 = (size_t)(n0 + (a0 >> 6)) * ldB + ((a0 & 63) >> 1);
        srcB1 = (size_t)(n0 + (a1 >> 6)) * ldB + ((a1 & 63) >> 1);
    }
    auto stageA = [&](int par, int kh, int kt_src) {
        const short* s = Ab + kt_src * 64 + kh * 32;
        short* d = &lds[(par * 2 + kh) * 4096 + t * 8];
        gload_lds16(s + srcA0, d);
        gload_lds16(s + srcA1, d + 2048);
    };
    auto stageB = [&](int par, int kh, int kt_src) {
        const short* s = Bb + kt_src * 64 + kh * 32;
        short* d = &lds[16384 + (par * 2 + kh) * 4096 + t * 8];
        gload_lds16(s + srcB0, d);
        gload_lds16(s + srcB1, d + 2048);
    };

    // fragment ds_read byte offsets within slot (swizzled), K-invariant
    int aoffs[4], boffs[4];
#pragma unroll
    for (int fi = 0; fi < 4; ++fi) {
        int row = wm * 64 + fi * 16 + fr;         // 0..127
        int off = row * 64 + cb;
        aoffs[fi] = off ^ (((off >> 7) & 3) << 4);
    }
#pragma unroll
    for (int fj = 0; fj < 4; ++fj) {
        int row = wn * 64 + fj * 16 + fr;         // 0..127
        int off = row * 64 + cb;
        boffs[fj] = off ^ (((off >> 7) & 3) << 4);
    }

    f32x4 acc[4][4];
#pragma unroll
    for (int i = 0; i < 4; ++i)
#pragma unroll
        for (int j = 0; j < 4; ++j) acc[i][j] = (f32x4){0.f, 0.f, 0.f, 0.f};

    const int NT = K >> 6;
    const char* L = (const char*)lds;

    // prologue: 12 per-thread loads
    stageA(0, 0, 0); stageB(0, 0, 0);
    stageA(0, 1, 0); stageB(0, 1, 0);
    stageA(1, 0, 1); stageB(1, 0, 1);

    for (int kt = 0; kt < NT; ++kt) {
        const int par = kt & 1;
        const int AB0 = (par * 2) * 8192;         // byte bases
        const int AB1 = AB0 + 8192;
        const int BB0 = 32768 + (par * 2) * 8192;
        const int BB1 = BB0 + 8192;

        bf16x8 af0, af1, af2, af3, bf0, bf1;

        // ---------- phase 0: ks=0, fj 0-1 ----------
        if (kt == NT - 1) asm volatile("s_waitcnt vmcnt(4)\n\ts_barrier" ::: "memory");
        else              asm volatile("s_waitcnt vmcnt(8)\n\ts_barrier" ::: "memory");
        af0 = *(const bf16x8*)(L + AB0 + aoffs[0]);
        af1 = *(const bf16x8*)(L + AB0 + aoffs[1]);
        af2 = *(const bf16x8*)(L + AB0 + aoffs[2]);
        af3 = *(const bf16x8*)(L + AB0 + aoffs[3]);
        bf0 = *(const bf16x8*)(L + BB0 + boffs[0]);
        bf1 = *(const bf16x8*)(L + BB0 + boffs[1]);
        if (kt + 1 < NT) stageA(par ^ 1, 1, kt + 1);
        __builtin_amdgcn_s_setprio(1);
        acc[0][0] = __builtin_amdgcn_mfma_f32_16x16x32_bf16(af0, bf0, acc[0][0], 0, 0, 0);
        acc[1][0] = __builtin_amdgcn_mfma_f32_16x16x32_bf16(af1, bf0, acc[1][0], 0, 0, 0);
        acc[2][0] = __builtin_amdgcn_mfma_f32_16x16x32_bf16(af2, bf0, acc[2][0], 0, 0, 0);
        acc[3][0] = __builtin_amdgcn_mfma_f32_16x16x32_bf16(af3, bf0, acc[3][0], 0, 0, 0);
        acc[0][1] = __builtin_amdgcn_mfma_f32_16x16x32_bf16(af0, bf1, acc[0][1], 0, 0, 0);
        acc[1][1] = __builtin_amdgcn_mfma_f32_16x16x32_bf16(af1, bf1, acc[1][1], 0, 0, 0);
        acc[2][1] = __builtin_amdgcn_mfma_f32_16x16x32_bf16(af2, bf1, acc[2][1], 0, 0, 0);
        acc[3][1] = __builtin_amdgcn_mfma_f32_16x16x32_bf16(af3, bf1, acc[3][1], 0, 0, 0);
        __builtin_amdgcn_s_setprio(0);
        asm volatile("s_waitcnt lgkmcnt(0)\n\ts_barrier" ::: "memory");

        // ---------- phase 1: ks=0, fj 2-3 ----------
        bf0 = *(const bf16x8*)(L + BB0 + boffs[2]);
        bf1 = *(const bf16x8*)(L + BB0 + boffs[3]);
        if (kt + 1 < NT) stageB(par ^ 1, 1, kt + 1);
        __builtin_amdgcn_s_setprio(1);
        acc[0][2] = __builtin_amdgcn_mfma_f32_16x16x32_bf16(af0, bf0, acc[0][2], 0, 0, 0);
        acc[1][2] = __builtin_amdgcn_mfma_f32_16x16x32_bf16(af1, bf0, acc[1][2], 0, 0, 0);
        acc[2][2] = __builtin_amdgcn_mfma_f32_16x16x32_bf16(af2, bf0, acc[2][2], 0, 0, 0);
        acc[3][2] = __builtin_amdgcn_mfma_f32_16x16x32_bf16(af3, bf0, acc[3][2], 0, 0, 0);
        acc[0][3] = __builtin_amdgcn_mfma_f32_16x16x32_bf16(af0, bf1, acc[0][3], 0, 0, 0);
        acc[1][3] = __builtin_amdgcn_mfma_f32_16x16x32_bf16(af1, bf1, acc[1][3], 0, 0, 0);
        acc[2][3] = __builtin_amdgcn_mfma_f32_16x16x32_bf16(af2, bf1, acc[2][3], 0, 0, 0);
        acc[3][3] = __builtin_amdgcn_mfma_f32_16x16x32_bf16(af3, bf1, acc[3][3], 0, 0, 0);
        __builtin_amdgcn_s_setprio(0);
        asm volatile("s_waitcnt lgkmcnt(0)\n\ts_barrier" ::: "memory");

        // ---------- phase 2: ks=1, fj 0-1 ----------
        if (kt == NT - 1) asm volatile("s_waitcnt vmcnt(0)\n\ts_barrier" ::: "memory");
        else              asm volatile("s_waitcnt vmcnt(8)\n\ts_barrier" ::: "memory");
        af0 = *(const bf16x8*)(L + AB1 + aoffs[0]);
        af1 = *(const bf16x8*)(L + AB1 + aoffs[1]);
        af2 = *(const bf16x8*)(L + AB1 + aoffs[2]);
        af3 = *(const bf16x8*)(L + AB1 + aoffs[3]);
        bf0 = *(const bf16x8*)(L + BB1 + boffs[0]);
        bf1 = *(const bf16x8*)(L + BB1 + boffs[1]);
        if (kt + 2 < NT) stageA(par, 0, kt + 2);
        __builtin_amdgcn_s_setprio(1);
        acc[0][0] = __builtin_amdgcn_mfma_f32_16x16x32_bf16(af0, bf0, acc[0][0], 0, 0, 0);
        acc[1][0] = __builtin_amdgcn_mfma_f32_16x16x32_bf16(af1, bf0, acc[1][0], 0, 0, 0);
        acc[2][0] = __builtin_amdgcn_mfma_f32_16x16x32_bf16(af2, bf0, acc[2][0], 0, 0, 0);
        acc[3][0] = __builtin_amdgcn_mfma_f32_16x16x32_bf16(af3, bf0, acc[3][0], 0, 0, 0);
        acc[0][1] = __builtin_amdgcn_mfma_f32_16x16x32_bf16(af0, bf1, acc[0][1], 0, 0, 0);
        acc[1][1] = __builtin_amdgcn_mfma_f32_16x16x32_bf16(af1, bf1, acc[1][1], 0, 0, 0);
        acc[2][1] = __builtin_amdgcn_mfma_f32_16x16x32_bf16(af2, bf1, acc[2][1], 0, 0, 0);
        acc[3][1] = __builtin_amdgcn_mfma_f32_16x16x32_bf16(af3, bf1, acc[3][1], 0, 0, 0);
        __builtin_amdgcn_s_setprio(0);
        asm volatile("s_waitcnt lgkmcnt(0)\n\ts_barrier" ::: "memory");

        // ---------- phase 3: ks=1, fj 2-3 ----------
        bf0 = *(const bf16x8*)(L + BB1 + boffs[2]);
        bf1 = *(const bf16x8*)(L + BB1 + boffs[3]);
        if (kt + 2 < NT) stageB(par, 0, kt + 2);
        __builtin_amdgcn_s_setprio(1);
        acc[0][2] = __builtin_amdgcn_mfma_f32_16x16x32_bf16(af0, bf0, acc[0][2], 0, 0, 0);
        acc[1][2] = __builtin_amdgcn_mfma_f32_16x16x32_bf16(af1, bf0, acc[1][2], 0, 0, 0);
        acc[2][2] = __builtin_amdgcn_mfma_f32_16x16x32_bf16(af2, bf0, acc[2][2], 0, 0, 0);
        acc[3][2] = __builtin_amdgcn_mfma_f32_16x16x32_bf16(af3, bf0, acc[3][2], 0, 0, 0);
        acc[0][3] = __builtin_amdgcn_mfma_f32_16x16x32_bf16(af0, bf1, acc[0][3], 0, 0, 0);
        acc[1][3] = __builtin_amdgcn_mfma_f32_16x16x32_bf16(af1, bf1, acc[1][3], 0, 0, 0);
        acc[2][3] = __builtin_amdgcn_mfma_f32_16x16x32_bf16(af2, bf1, acc[2][3], 0, 0, 0);
        acc[3][3] = __builtin_amdgcn_mfma_f32_16x16x32_bf16(af3, bf1, acc[3][3], 0, 0, 0);
        __builtin_amdgcn_s_setprio(0);
        asm volatile("s_waitcnt lgkmcnt(0)\n\ts_barrier" ::: "memory");
    }

    // C/D layout: col = lane&15, row = (lane>>4)*4 + reg  [m89-verified]
    const int rq = (lane >> 4) * 4;
#pragma unroll
    for (int fi = 0; fi < 4; ++fi) {
#pragma unroll
        for (int rg = 0; rg < 4; ++rg) {
            int row = m0 + wm * 64 + fi * 16 + rq + rg;
            float bm = (BIASMODE == 1) ? bias[row] : 0.f;
#pragma unroll
            for (int fj = 0; fj < 4; ++fj) {
                int col = n0 + wn * 64 + fj * 16 + fr;
                float vv = acc[fi][fj][rg] * alpha + bm;
                if (BIASMODE == 2) vv += bias[col];
                size_t off = (size_t)row * ldC + col;
                if (HASRES) vv += res[(size_t)bz * sR + off];
                if (OUTF32) ((float*)Cm)[(size_t)bz * sC + off] = vv;
                else ((unsigned short*)Cm)[(size_t)bz * sC + off] = f2bf(vv);
            }
        }
    }
}

// ---------------- in-place bf16 row softmax over 1024 ----------------
__global__ __launch_bounds__(256) void softmax_kernel(unsigned short* __restrict__ attn)
{
    size_t row = blockIdx.x;
    unsigned short* p = attn + row * HW_;
    ushort4 raw = reinterpret_cast<ushort4*>(p)[threadIdx.x];
    float v0 = bf2f(raw.x), v1 = bf2f(raw.y), v2 = bf2f(raw.z), v3 = bf2f(raw.w);

    float mx = fmaxf(fmaxf(v0, v1), fmaxf(v2, v3));
    for (int off = 32; off; off >>= 1) mx = fmaxf(mx, __shfl_down(mx, off, 64));
    __shared__ float redm[4], reds[4];
    int lane = threadIdx.x & 63, wid = threadIdx.x >> 6;
    if (lane == 0) redm[wid] = mx;
    __syncthreads();
    mx = fmaxf(fmaxf(redm[0], redm[1]), fmaxf(redm[2], redm[3]));

    v0 = __expf(v0 - mx); v1 = __expf(v1 - mx);
    v2 = __expf(v2 - mx); v3 = __expf(v3 - mx);
    float sum = v0 + v1 + v2 + v3;
    for (int off = 32; off; off >>= 1) sum += __shfl_down(sum, off, 64);
    if (lane == 0) reds[wid] = sum;
    __syncthreads();
    sum = reds[0] + reds[1] + reds[2] + reds[3];

    float inv = 1.f / sum;
    ushort4 o;
    o.x = f2bf(v0 * inv); o.y = f2bf(v1 * inv);
    o.z = f2bf(v2 * inv); o.w = f2bf(v3 * inv);
    reinterpret_cast<ushort4*>(p)[threadIdx.x] = o;
}

extern "C" void kernel_launch(void* const* d_in, const int* in_sizes, int n_in,
                              void* d_out, int out_size, void* d_ws, size_t ws_size,
                              hipStream_t stream)
{
    const float* x        = (const float*)d_in[0];
    // d_in[1] = temb : unused by the reference
    const float* gn_scale = (const float*)d_in[2];
    const float* gn_bias  = (const float*)d_in[3];
    const float* wq = (const float*)d_in[4];
    const float* bq = (const float*)d_in[5];
    const float* wk = (const float*)d_in[6];
    const float* bk = (const float*)d_in[7];
    const float* wv = (const float*)d_in[8];
    const float* bv = (const float*)d_in[9];
    const float* wo = (const float*)d_in[10];
    const float* bo = (const float*)d_in[11];
    float* out = (float*)d_out;

    // workspace layout (bf16 elements)
    short* ws = (short*)d_ws;
    const size_t E = (size_t)B_ * C_ * HW_;        // 8388608
    short* hn_t = ws;                              // [b][i][c]          E
    short* qk_t = hn_t + E;                        // [b*i][q||k]        2E
    short* v    = qk_t + 2 * E;                    // [b][c][j]          E
    short* ao_t = v + E;                           // [b][i][c]          E
    short* attn = ao_t + E;                        // [b][i][j]          2E
    short* wsq  = attn + 2 * E;                    // wq||wk||wv||wo bf16
    short* wsk  = wsq + (size_t)C_ * C_;
    short* wsv  = wsk + (size_t)C_ * C_;
    short* wso  = wsv + (size_t)C_ * C_;
    float* bqk  = (float*)(wso + (size_t)C_ * C_); // 1024 f32
    float2* stats = (float2*)(bqk + 1024);         // 512 float2

    const float inv_sqrt_c = 0.044194173824159216f;   // 512^-0.5

    f2bf4_kernel<<<dim3(1024), 256, 0, stream>>>(
        wq, wk, wv, wo,
        (unsigned short*)wsq, (unsigned short*)wsk,
        (unsigned short*)wsv, (unsigned short*)wso);
    bias_concat<<<dim3(2), 256, 0, stream>>>(bq, bk, bqk);

    gn_stats<<<dim3(B_ * G_), 256, 0, stream>>>(x, stats);
    gn_apply<<<dim3(HW_ / 64, C_ / 64, B_), 256, 0, stream>>>(
        x, stats, gn_scale, gn_bias, (unsigned short*)hn_t);

    // fused QK projection: qk_t[m][n] = sum_c hn_t[m][c] * (wq||wk)[n][c] + bqk[n]
    dim3 gqk(HW_ / 128, (B_ * HW_) / 128, 1);      // (8, 128, 1)
    gemm_4w<0, 2, 0><<<gqk, 256, 0, stream>>>(
        hn_t, 0, C_, wsq, 0, C_, qk_t, 0, HW_, bqk, nullptr, 0, C_, 1.0f);

    // v[c][j] = sum_k wv[c][k] * hn_t[j][k] + bv[c]
    dim3 gv(HW_ / 128, C_ / 128, B_);              // (8, 4, 16)
    gemm_4w<0, 1, 0><<<gv, 256, 0, stream>>>(
        wsv, 0, C_, hn_t, CHW, C_, v, CHW, HW_, bv, nullptr, 0, C_, 1.0f);

    // attn[i][j] = (sum_c q[i][c] * k[j][c]) * C^-0.5   (q,k inside qk_t)
    dim3 gs(HW_ / 128, HW_ / 128, B_);             // (8, 8, 16)
    gemm_4w<0, 0, 0><<<gs, 256, 0, stream>>>(
        qk_t, HW2, HW_, qk_t + C_, HW2, HW_, attn, HW2, HW_,
        nullptr, nullptr, 0, C_, inv_sqrt_c);

    softmax_kernel<<<dim3(B_ * HW_), 256, 0, stream>>>((unsigned short*)attn);

    // ao_t[i][c] = sum_j attn[i][j] * v[c][j]
    dim3 gp(C_ / 128, HW_ / 128, B_);              // (4, 8, 16)
    gemm_4w<0, 0, 0><<<gp, 256, 0, stream>>>(
        attn, HW2, HW_, v, CHW, HW_, ao_t, CHW, C_, nullptr, nullptr, 0, HW_, 1.0f);

    // out[c][i] = x + sum_k wo[c][k] * ao_t[i][k] + bo[c]
    dim3 go(HW_ / 128, C_ / 128, B_);              // (8, 4, 16)
    gemm_4w<1, 1, 1><<<go, 256, 0, stream>>>(
        wso, 0, C_, ao_t, CHW, C_, out, CHW, HW_, bo, x, CHW, C_, 1.0f);
}